// Round 16
// baseline (302.522 us; speedup 1.0000x reference)
//
#include <hip/hip_runtime.h>

#define BTOT 4096
#define G 4               // batch items per block (one per wave)
#define NC 16
#define WIN 247
#define NBLK (BTOT / G)   // 1024 blocks

typedef float v2f __attribute__((ext_vector_type(2)));

// W table in LDS, v2f {Wr,Wi} per (tap m, channel c); m = t+9, t = global tap.
#define F2IDX(m, c) ((m) * 16 + (c) + ((m) >> 6) * 8)
#define WTSZ 4272         // F2IDX(264,15)+1

// ---------------- Single launch: conv + nonlinearity + projections + last-finisher BN ----------------
__global__ __launch_bounds__(256, 4) void k_main(
    const float* __restrict__ x,
    const float* __restrict__ Wr, const float* __restrict__ Wi,
    const float* __restrict__ Wnl, const float* __restrict__ Wc,
    const float* __restrict__ Wor, const float* __restrict__ Woi,
    const float* __restrict__ gamma, const float* __restrict__ beta,
    float* __restrict__ out, unsigned* __restrict__ ctl,
    float* __restrict__ ws_ab, float2* __restrict__ p2)
{
    __shared__ v2f WT[WTSZ];            // 34176 B
    __shared__ float Mlds[4 * 16 * 17]; // 4352 B, stride 17 (conflict-free)
    __shared__ float WoS[2 * 160];      // 1280 B
    __shared__ float WcS[4];
    __shared__ unsigned win_s;

    const int tid  = threadIdx.x;
    const int lane = tid & 63;
    const int wv   = tid >> 6;          // wave = one batch item
    const int jj   = lane >> 4;         // n-residue 0..3 (n = i*4 + jj)
    const int c    = lane & 15;         // channel
    const int b0   = blockIdx.x * G;

    // ---- stage W table (zero-padded, fp32) ----
    for (int idx = tid; idx < 265 * 16; idx += 256) {
        int m = idx >> 4, cc = idx & 15;
        int t = m - 9;
        v2f v = (v2f)(0.f);
        if (t >= 0 && t < WIN) { v.x = Wr[cc * WIN + t]; v.y = Wi[cc * WIN + t]; }
        WT[F2IDX(m, cc)] = v;
    }
    // ---- zero-diagonal neighbor matrices, stride 17 ----
    for (int idx = tid; idx < 1024; idx += 256) {
        int m  = idx >> 8;              // 0..3 : o = m>>1, part = m&1
        int cc = (idx >> 4) & 15;
        int j  = idx & 15;
        float v = 0.f;
        if (j != cc) {
            int jp = j - (j > cc);
            v = Wnl[cc * 60 + (m >> 1) * 30 + (m & 1) * 15 + jp];
        }
        Mlds[m * 272 + cc * 17 + j] = v;
    }
    if (tid < 160) { WoS[tid] = Wor[tid]; WoS[160 + tid] = Woi[tid]; }
    if (tid < 4) WcS[tid] = Wc[tid];
    __syncthreads();

    // x[b, n, c, ri] as v2f: step i loads v2f index i*64 + lane  (contiguous 512B per wave)
    const v2f* xq = (const v2f*)x + (size_t)(b0 + wv) * 4096 + lane;

    v2f acc[10];                        // {real, imag} accumulators (n ≡ jj mod 4 partials)
    v2f win[14];                        // per-lane W ring; slot = slotbase % 14, tap = slotbase + jj
    v2f xr[8];                          // depth-8 x prefetch ring
    #pragma unroll
    for (int w = 0; w < 10; ++w) acc[w] = (v2f)(0.f);

    #pragma unroll
    for (int d = 0; d < 14; ++d) win[d] = WT[F2IDX(d + jj, c)];
    #pragma unroll
    for (int j = 0; j < 8; ++j) xr[j] = xq[j * 64];

    // ---- conv: 64 steps; n = i*4 + jj; x depth-8; W ring slides 4/step ----
    #pragma unroll
    for (int i = 0; i < 64; ++i) {
        v2f xv = xr[i & 7];
        if (i < 56) xr[i & 7] = xq[(i + 8) * 64];
        #pragma unroll
        for (int w = 0; w < 10; ++w) {
            v2f wt = win[(i * 4 + 9 - w) % 14];   // tap m = i*4 + jj + 9 - w
            acc[w] = __builtin_elementwise_fma(xv, wt, acc[w]);
        }
        #pragma unroll
        for (int d = 0; d < 4; ++d) {
            const int mb = i * 4 + 14 + d;        // slotbase to refill
            if (mb <= 261) win[mb % 14] = WT[F2IDX(mb + jj, c)];
        }
    }

    // ---- reduce over jj (lane bits 4,5) ----
    #pragma unroll
    for (int w = 0; w < 10; ++w) {
        acc[w].x += __shfl_xor(acc[w].x, 16);  acc[w].x += __shfl_xor(acc[w].x, 32);
        acc[w].y += __shfl_xor(acc[w].y, 16);  acc[w].y += __shfl_xor(acc[w].y, 32);
    }

    __syncthreads();                    // all conv reads of WT done -> safe to alias
    float* S    = (float*)WT;
    float* fbuf = S;                    // [b][c][{r,i}][w] : G*320 = 1280 f
    float* crS  = S + 1280;             // 640 f
    float* ciS  = S + 1920;             // 640 f

    // ---- amp nonlinearity (fully reduced in-register) ----
    if (lane < 16) {
        #pragma unroll
        for (int w = 0; w < 10; ++w) {
            float fr = acc[w].x, fi = acc[w].y;
            float a  = fr * fr + fi * fi;
            fbuf[wv * 320 + c * 20 + w]      = a * fr;
            fbuf[wv * 320 + c * 20 + 10 + w] = a * fi;
        }
    }
    __syncthreads();

    // ---- phase 3: neighbor einsum + coeff + output-window weights ----
    const float* M0r = Mlds;
    const float* M0i = Mlds + 272;
    const float* M1r = Mlds + 544;
    const float* M1i = Mlds + 816;
    for (int idx = tid; idx < G * 160; idx += 256) {
        int bb = idx / 160; int r = idx - bb * 160;
        int cc = r / 10;    int w = r - cc * 10;
        const float* f3 = fbuf + bb * 320;
        float s0 = 0.f, s1 = 0.f;
        #pragma unroll
        for (int j = 0; j < NC; ++j) {
            float f3r = f3[j * 20 + w];
            float f3i = f3[j * 20 + 10 + w];
            s0 = fmaf(f3r, M0r[cc * 17 + j], fmaf(f3i, M0i[cc * 17 + j], s0));
            s1 = fmaf(f3r, M1r[cc * 17 + j], fmaf(f3i, M1i[cc * 17 + j], s1));
        }
        float p0 = s0 * WcS[0] + s1 * WcS[1];
        float p1 = s0 * WcS[2] + s1 * WcS[3];
        crS[idx] = p0 * WoS[cc * 10 + w];
        ciS[idx] = p1 * WoS[160 + cc * 10 + w];
    }
    __syncthreads();

    // ---- phase 4: per-(b,c) outputs in registers + per-block BN partials ----
    float orr = 0.f, oii = 0.f;
    if (tid < G * NC) {                 // tid = bb*16+cc, single wave
        int bb = tid >> 4; int cc = tid & 15;
        #pragma unroll
        for (int w = 0; w < 10; ++w) {
            orr += crS[bb * 160 + cc * 10 + w];
            oii += ciS[bb * 160 + cc * 10 + w];
        }
        float s1 = orr + oii;
        float q1 = orr * orr + oii * oii;
        s1 += __shfl_xor(s1, 16);  s1 += __shfl_xor(s1, 32);   // reduce over bb
        q1 += __shfl_xor(q1, 16);  q1 += __shfl_xor(q1, 32);
        if (tid < NC)
            p2[tid * NBLK + blockIdx.x] = make_float2(s1, q1);
    }
    __threadfence();                    // partials globally visible before counter bump
    __syncthreads();

    // ---- last-finisher reduces (all 1024 blocks co-resident: 4/CU x 256 CU) ----
    if (tid == 0) {
        unsigned old = atomicAdd(ctl, 1u);
        win_s = (old == (unsigned)(NBLK - 1));
    }
    __syncthreads();
    if (win_s) {
        __threadfence();                // acquire side for p2
        int cch = tid >> 4, t = tid & 15;
        float s = 0.f, q = 0.f;
        #pragma unroll 8
        for (int k = 0; k < NBLK / 16; ++k) {
            float2 v = p2[cch * NBLK + t + 16 * k];
            s += v.x; q += v.y;
        }
        #pragma unroll
        for (int off = 1; off < 16; off <<= 1) {
            s += __shfl_xor(s, off);
            q += __shfl_xor(q, off);
        }
        if (t == 0) {
            const float inv_n = 1.f / (BTOT * 2.f);
            float mu  = s * inv_n;
            float var = q * inv_n - mu * mu;
            float sc  = gamma[cch] * rsqrtf(var + 1e-5f);
            ws_ab[cch]      = sc;
            ws_ab[16 + cch] = beta[cch] - mu * sc;
            __threadfence();            // writer-side fence before release
        }
        __syncthreads();
        if (tid == 0)
            __hip_atomic_store(ctl + 1, 1u, __ATOMIC_RELEASE, __HIP_MEMORY_SCOPE_AGENT);
    } else {
        if (tid == 0) {
            while (__hip_atomic_load(ctl + 1, __ATOMIC_ACQUIRE, __HIP_MEMORY_SCOPE_AGENT) == 0u)
                __builtin_amdgcn_s_sleep(8);
        }
        __syncthreads();
    }

    // ---- apply affine, single out write from registers ----
    if (tid < G * NC) {
        int bb = tid >> 4; int cc = tid & 15;
        float a = ws_ab[cc], b = ws_ab[16 + cc];
        size_t o = ((size_t)(b0 + bb) * NC + cc) * 2;
        out[o]     = orr * a + b;
        out[o + 1] = oii * a + b;
    }
}

extern "C" void kernel_launch(void* const* d_in, const int* in_sizes, int n_in,
                              void* d_out, int out_size, void* d_ws, size_t ws_size,
                              hipStream_t stream)
{
    const float* x    = (const float*)d_in[0];
    const float* Wr   = (const float*)d_in[1];
    const float* Wi   = (const float*)d_in[2];
    const float* Wnl  = (const float*)d_in[3];
    const float* Wc   = (const float*)d_in[4];
    const float* Wor  = (const float*)d_in[5];
    const float* Woi  = (const float*)d_in[6];
    const float* gam  = (const float*)d_in[7];
    const float* bet  = (const float*)d_in[8];
    float* out = (float*)d_out;

    // ws layout: [0..63] ctl (counter, flag) | [64..191] ws_ab (32 f) | [256..] p2 (16*1024 float2)
    unsigned* ctl  = (unsigned*)d_ws;
    float* ws_ab   = (float*)d_ws + 16;
    float2* p2     = (float2*)((char*)d_ws + 256);

    hipMemsetAsync(d_ws, 0, 256, stream);   // reset counter/flag (+ab) every call

    k_main<<<NBLK, 256, 0, stream>>>(x, Wr, Wi, Wnl, Wc, Wor, Woi, gam, bet,
                                     out, ctl, ws_ab, p2);
}

// Round 17
// 43.484 us; speedup vs baseline: 6.9570x; 6.9570x over previous
//
#include <hip/hip_runtime.h>

#define BTOT 4096
#define G 4               // batch items per block (one per wave)
#define NC 16
#define WIN 247
#define NBLK (BTOT / G)   // 1024 blocks

typedef float v2f __attribute__((ext_vector_type(2)));

// W table in LDS, v2f {Wr,Wi} per (tap m, channel c); m = t+9, t = global tap.
#define F2IDX(m, c) ((m) * 16 + (c) + ((m) >> 6) * 8)
#define WTSZ 4272         // F2IDX(264,15)+1

// ---------------- Kernel 1: conv (contiguous 512B wave loads) + nonlinearity + projections ----------------
__global__ __launch_bounds__(256, 4) void k_main(
    const float* __restrict__ x,
    const float* __restrict__ Wr, const float* __restrict__ Wi,
    const float* __restrict__ Wnl, const float* __restrict__ Wc,
    const float* __restrict__ Wor, const float* __restrict__ Woi,
    float* __restrict__ out, float2* __restrict__ p2)
{
    __shared__ v2f WT[WTSZ];            // 34176 B
    __shared__ float Mlds[4 * 16 * 17]; // 4352 B, stride 17 (conflict-free)
    __shared__ float WoS[2 * 160];      // 1280 B
    __shared__ float WcS[4];

    const int tid  = threadIdx.x;
    const int lane = tid & 63;
    const int wv   = tid >> 6;          // wave = one batch item
    const int jj   = lane >> 4;         // n-residue 0..3 (n = i*4 + jj)
    const int c    = lane & 15;         // channel
    const int b0   = blockIdx.x * G;

    // ---- stage W table (zero-padded, fp32) ----
    for (int idx = tid; idx < 265 * 16; idx += 256) {
        int m = idx >> 4, cc = idx & 15;
        int t = m - 9;
        v2f v = (v2f)(0.f);
        if (t >= 0 && t < WIN) { v.x = Wr[cc * WIN + t]; v.y = Wi[cc * WIN + t]; }
        WT[F2IDX(m, cc)] = v;
    }
    // ---- zero-diagonal neighbor matrices, stride 17 ----
    for (int idx = tid; idx < 1024; idx += 256) {
        int m  = idx >> 8;              // 0..3 : o = m>>1, part = m&1
        int cc = (idx >> 4) & 15;
        int j  = idx & 15;
        float v = 0.f;
        if (j != cc) {
            int jp = j - (j > cc);
            v = Wnl[cc * 60 + (m >> 1) * 30 + (m & 1) * 15 + jp];
        }
        Mlds[m * 272 + cc * 17 + j] = v;
    }
    if (tid < 160) { WoS[tid] = Wor[tid]; WoS[160 + tid] = Woi[tid]; }
    if (tid < 4) WcS[tid] = Wc[tid];
    __syncthreads();

    // x[b, n, c, ri] as v2f: step i loads v2f index i*64 + lane  (contiguous 512B per wave)
    const v2f* xq = (const v2f*)x + (size_t)(b0 + wv) * 4096 + lane;

    v2f acc[10];                        // {real, imag} accumulators (n ≡ jj mod 4 partials)
    v2f win[14];                        // per-lane W ring; slot = (slotbase) % 14, tap = slotbase + jj
    v2f xr[8];                          // depth-8 x prefetch ring
    #pragma unroll
    for (int w = 0; w < 10; ++w) acc[w] = (v2f)(0.f);

    #pragma unroll
    for (int d = 0; d < 14; ++d) win[d] = WT[F2IDX(d + jj, c)];
    #pragma unroll
    for (int j = 0; j < 8; ++j) xr[j] = xq[j * 64];

    // ---- conv: 64 steps; n = i*4 + jj; x depth-8; W ring slides 4/step ----
    #pragma unroll
    for (int i = 0; i < 64; ++i) {
        v2f xv = xr[i & 7];
        if (i < 56) xr[i & 7] = xq[(i + 8) * 64];
        #pragma unroll
        for (int w = 0; w < 10; ++w) {
            v2f wt = win[(i * 4 + 9 - w) % 14];   // tap m = i*4 + jj + 9 - w
            acc[w] = __builtin_elementwise_fma(xv, wt, acc[w]);
        }
        #pragma unroll
        for (int d = 0; d < 4; ++d) {
            const int mb = i * 4 + 14 + d;        // slotbase to refill
            if (mb <= 261) win[mb % 14] = WT[F2IDX(mb + jj, c)];
        }
    }

    // ---- reduce over jj (lane bits 4,5) ----
    #pragma unroll
    for (int w = 0; w < 10; ++w) {
        acc[w].x += __shfl_xor(acc[w].x, 16);  acc[w].x += __shfl_xor(acc[w].x, 32);
        acc[w].y += __shfl_xor(acc[w].y, 16);  acc[w].y += __shfl_xor(acc[w].y, 32);
    }

    __syncthreads();                    // all conv reads of WT done -> safe to alias
    float* S    = (float*)WT;
    float* fbuf = S;                    // [b][c][{r,i}][w] : G*320 = 1280 f
    float* crS  = S + 1280;             // 640 f
    float* ciS  = S + 1920;             // 640 f

    // ---- amp nonlinearity (fully reduced in-register) ----
    if (lane < 16) {
        #pragma unroll
        for (int w = 0; w < 10; ++w) {
            float fr = acc[w].x, fi = acc[w].y;
            float a  = fr * fr + fi * fi;
            fbuf[wv * 320 + c * 20 + w]      = a * fr;
            fbuf[wv * 320 + c * 20 + 10 + w] = a * fi;
        }
    }
    __syncthreads();

    // ---- phase 3: neighbor einsum + coeff + output-window weights ----
    const float* M0r = Mlds;
    const float* M0i = Mlds + 272;
    const float* M1r = Mlds + 544;
    const float* M1i = Mlds + 816;
    for (int idx = tid; idx < G * 160; idx += 256) {
        int bb = idx / 160; int r = idx - bb * 160;
        int cc = r / 10;    int w = r - cc * 10;
        const float* f3 = fbuf + bb * 320;
        float s0 = 0.f, s1 = 0.f;
        #pragma unroll
        for (int j = 0; j < NC; ++j) {
            float f3r = f3[j * 20 + w];
            float f3i = f3[j * 20 + 10 + w];
            s0 = fmaf(f3r, M0r[cc * 17 + j], fmaf(f3i, M0i[cc * 17 + j], s0));
            s1 = fmaf(f3r, M1r[cc * 17 + j], fmaf(f3i, M1i[cc * 17 + j], s1));
        }
        float p0 = s0 * WcS[0] + s1 * WcS[1];
        float p1 = s0 * WcS[2] + s1 * WcS[3];
        crS[idx] = p0 * WoS[cc * 10 + w];
        ciS[idx] = p1 * WoS[160 + cc * 10 + w];
    }
    __syncthreads();

    // ---- phase 4: sum over w, write raw out + per-block reduced BN partials ----
    if (tid < G * NC) {                 // tid = bb*16+cc, single wave
        int bb = tid >> 4; int cc = tid & 15;
        float orr = 0.f, oii = 0.f;
        #pragma unroll
        for (int w = 0; w < 10; ++w) {
            orr += crS[bb * 160 + cc * 10 + w];
            oii += ciS[bb * 160 + cc * 10 + w];
        }
        size_t o = ((size_t)(b0 + bb) * NC + cc) * 2;
        out[o]     = orr;
        out[o + 1] = oii;
        float s1 = orr + oii;
        float q1 = orr * orr + oii * oii;
        s1 += __shfl_xor(s1, 16);  s1 += __shfl_xor(s1, 32);   // reduce over bb
        q1 += __shfl_xor(q1, 16);  q1 += __shfl_xor(q1, 32);
        if (tid < NC)
            p2[tid * NBLK + blockIdx.x] = make_float2(s1, q1);
    }
}

// ---------------- Kernel 2: BN stats (redundant per block, L2-hot) + apply ----------------
__global__ __launch_bounds__(256) void k_bn(
    const float2* __restrict__ p2,
    const float* __restrict__ gamma, const float* __restrict__ beta,
    float* __restrict__ out)
{
    __shared__ float A[16], Bb[16];
    const int tid = threadIdx.x;
    const int cch = tid >> 4;           // channel 0..15
    const int t   = tid & 15;

    float s = 0.f, q = 0.f;
    #pragma unroll 8
    for (int k = 0; k < NBLK / 16; ++k) {   // 64 entries per thread
        float2 v = p2[cch * NBLK + t + 16 * k];
        s += v.x; q += v.y;
    }
    #pragma unroll
    for (int off = 1; off < 16; off <<= 1) {
        s += __shfl_xor(s, off);
        q += __shfl_xor(q, off);
    }
    if (t == 0) {
        const float inv_n = 1.f / (BTOT * 2.f);
        float mu  = s * inv_n;
        float var = q * inv_n - mu * mu;
        float sc  = gamma[cch] * rsqrtf(var + 1e-5f);
        A[cch]  = sc;
        Bb[cch] = beta[cch] - mu * sc;
    }
    __syncthreads();

    // apply: out as float4 (channels cp, cp+1); 32768 float4 total, 512/block
    float4* o4 = (float4*)out;
    const int base = blockIdx.x * 512;
    #pragma unroll
    for (int i = 0; i < 2; ++i) {
        int f = base + i * 256 + tid;
        float4 v = o4[f];
        int cp = (f & 7) * 2;
        v.x = v.x * A[cp]     + Bb[cp];
        v.y = v.y * A[cp]     + Bb[cp];
        v.z = v.z * A[cp + 1] + Bb[cp + 1];
        v.w = v.w * A[cp + 1] + Bb[cp + 1];
        o4[f] = v;
    }
}

extern "C" void kernel_launch(void* const* d_in, const int* in_sizes, int n_in,
                              void* d_out, int out_size, void* d_ws, size_t ws_size,
                              hipStream_t stream)
{
    const float* x    = (const float*)d_in[0];
    const float* Wr   = (const float*)d_in[1];
    const float* Wi   = (const float*)d_in[2];
    const float* Wnl  = (const float*)d_in[3];
    const float* Wc   = (const float*)d_in[4];
    const float* Wor  = (const float*)d_in[5];
    const float* Woi  = (const float*)d_in[6];
    const float* gam  = (const float*)d_in[7];
    const float* bet  = (const float*)d_in[8];
    float* out = (float*)d_out;
    float2* p2 = (float2*)d_ws;         // 16 * 1024 float2 = 128 KB

    k_main<<<NBLK, 256, 0, stream>>>(x, Wr, Wi, Wnl, Wc, Wor, Woi, out, p2);
    k_bn<<<64, 256, 0, stream>>>(p2, gam, bet, out);
}